// Round 1
// baseline (1222.101 us; speedup 1.0000x reference)
//
#include <hip/hip_runtime.h>
#include <hip/hip_bf16.h>

// EdgeConv: B=8, C=64, N=4096, OUT=64, K=20
// h[b,o,n,k] = z[b,n,o] - y[b,idx_k,o]  with y = W1·x, z = (W1+W2)·x
// out = leakyrelu((z - min/max_k y)*inv + bias)    (monotone fold of max_k)
#define BB 8
#define CC 64
#define NN 4096
#define OO 64
#define KK 20
#define MS 24          // per-quarter candidate list size (margin 4 over K=20)
#define CANDS 96       // 4 quarters * 24

// ---------------- Kernel 1: transpose + xx + y/z matvecs ----------------
__global__ __launch_bounds__(256, 2) void k_prep(
    const float* __restrict__ x, const float* __restrict__ W,
    float* __restrict__ xt, float* __restrict__ yT, float* __restrict__ zT,
    double* __restrict__ xxd, float* __restrict__ xxf)
{
    __shared__ float wS[8192];           // W row-major [o][128], 32 KB
    int tid = threadIdx.x;
    #pragma unroll
    for (int i = 0; i < 32; ++i) wS[tid + 256*i] = W[tid + 256*i];
    __syncthreads();

    int b = blockIdx.x >> 4;                       // 16 blocks per b
    int n = ((blockIdx.x & 15) << 8) + tid;

    float xv[64];
    double xx = 0.0;
    #pragma unroll
    for (int c = 0; c < 64; ++c) {
        float v = x[((size_t)(b*64 + c) << 12) + n];   // coalesced
        xv[c] = v;
        xx += (double)v * (double)v;
    }
    size_t rowbase = ((size_t)b*NN + n) * 64;
    #pragma unroll
    for (int c4 = 0; c4 < 16; ++c4)
        ((float4*)(xt + rowbase))[c4] =
            make_float4(xv[4*c4], xv[4*c4+1], xv[4*c4+2], xv[4*c4+3]);
    xxd[b*NN + n] = xx;
    xxf[b*NN + n] = (float)xx;

    // y = W1·x, z = (W1+W2)·x, layout [b][n][o] (contiguous o for gather)
    for (int o0 = 0; o0 < 64; o0 += 16) {
        float yv[16], zv[16];
        #pragma unroll
        for (int i = 0; i < 16; ++i) {
            const float* w1 = wS + (size_t)(o0 + i) * 128;
            float a1 = 0.f, a2 = 0.f;
            #pragma unroll
            for (int c = 0; c < 64; ++c) {
                a1 = fmaf(w1[c],      xv[c], a1);
                a2 = fmaf(w1[64 + c], xv[c], a2);
            }
            yv[i] = a1; zv[i] = a1 + a2;
        }
        float4* yp = (float4*)(yT + rowbase + o0);
        float4* zp = (float4*)(zT + rowbase + o0);
        #pragma unroll
        for (int i4 = 0; i4 < 4; ++i4) {
            yp[i4] = make_float4(yv[4*i4], yv[4*i4+1], yv[4*i4+2], yv[4*i4+3]);
            zp[i4] = make_float4(zv[4*i4], zv[4*i4+1], zv[4*i4+2], zv[4*i4+3]);
        }
    }
}

// ---------------- Kernel 2: approx top-24 per m-quarter ----------------
// block = 4 waves; wave w handles 64 rows x m-range [w*1024, w*1024+1024)
// score[m] = 2*dot(x_n, x_m) - xx[m]  (row-constant -xx[n] dropped)
__global__ __launch_bounds__(256, 2) void k_topk(
    const float* __restrict__ xt, const float* __restrict__ xxf,
    unsigned short* __restrict__ cand)
{
    __shared__ float xmS[4][64*64];      // exactly 64 KB
    int tid = threadIdx.x;
    int w = tid >> 6, lane = tid & 63;
    int b  = blockIdx.x >> 6;
    int n0 = (blockIdx.x & 63) << 6;
    int n  = n0 + lane;

    // own row in registers
    float xr[64];
    {
        const float4* xrg = (const float4*)(xt + ((size_t)b*NN + n) * 64);
        #pragma unroll
        for (int i = 0; i < 16; ++i) {
            float4 v = xrg[i];
            xr[4*i] = v.x; xr[4*i+1] = v.y; xr[4*i+2] = v.z; xr[4*i+3] = v.w;
        }
    }

    float val[MS]; int idx[MS];
    #pragma unroll
    for (int i = 0; i < MS; ++i) { val[i] = -__builtin_inff(); idx[i] = 0; }
    float T = -__builtin_inff();

    int mstart = w << 10;
    #pragma unroll 1
    for (int chunk = 0; chunk < 16; ++chunk) {
        int mbase = mstart + (chunk << 6);
        // stage 64 m-rows (16 KB) into this wave's LDS region
        {
            const float4* src = (const float4*)(xt + ((size_t)b*NN + mbase) * 64);
            float4* dst = (float4*)(xmS[w]);
            #pragma unroll
            for (int i = 0; i < 16; ++i) dst[lane + (i << 6)] = src[lane + (i << 6)];
        }
        __syncthreads();

        #pragma unroll 1
        for (int r8 = 0; r8 < 8; ++r8) {
            float s[8];
            #pragma unroll
            for (int j = 0; j < 8; ++j) {
                int ml = (r8 << 3) + j;
                const float4* mv = (const float4*)(xmS[w] + (ml << 6));
                float a0 = 0.f, a1 = 0.f, a2 = 0.f, a3 = 0.f;
                #pragma unroll
                for (int c4 = 0; c4 < 4; ++c4) {
                    float4 v0 = mv[c4*4+0], v1 = mv[c4*4+1], v2 = mv[c4*4+2], v3 = mv[c4*4+3];
                    a0 = fmaf(xr[c4*16+ 0], v0.x, a0); a0 = fmaf(xr[c4*16+ 1], v0.y, a0);
                    a0 = fmaf(xr[c4*16+ 2], v0.z, a0); a0 = fmaf(xr[c4*16+ 3], v0.w, a0);
                    a1 = fmaf(xr[c4*16+ 4], v1.x, a1); a1 = fmaf(xr[c4*16+ 5], v1.y, a1);
                    a1 = fmaf(xr[c4*16+ 6], v1.z, a1); a1 = fmaf(xr[c4*16+ 7], v1.w, a1);
                    a2 = fmaf(xr[c4*16+ 8], v2.x, a2); a2 = fmaf(xr[c4*16+ 9], v2.y, a2);
                    a2 = fmaf(xr[c4*16+10], v2.z, a2); a2 = fmaf(xr[c4*16+11], v2.w, a2);
                    a3 = fmaf(xr[c4*16+12], v3.x, a3); a3 = fmaf(xr[c4*16+13], v3.y, a3);
                    a3 = fmaf(xr[c4*16+14], v3.z, a3); a3 = fmaf(xr[c4*16+15], v3.w, a3);
                }
                s[j] = 2.f * ((a0 + a1) + (a2 + a3)) - xxf[b*NN + mbase + ml];
            }
            float rmax = s[0];
            #pragma unroll
            for (int j = 1; j < 8; ++j) rmax = fmaxf(rmax, s[j]);
            if (__any(rmax > T)) {
                #pragma unroll
                for (int j = 0; j < 8; ++j) {
                    bool doIns = s[j] > T;
                    if (__any(doIns)) {
                        int mg = mbase + (r8 << 3) + j;
                        bool done = false;
                        #pragma unroll
                        for (int t = 0; t < MS; ++t) {
                            bool c2 = doIns && !done && (val[t] == T);
                            val[t] = c2 ? s[j] : val[t];
                            idx[t] = c2 ? mg   : idx[t];
                            done = done || c2;
                        }
                        T = val[0];
                        #pragma unroll
                        for (int t = 1; t < MS; ++t) T = fminf(T, val[t]);
                    }
                }
            }
        }
        __syncthreads();
    }

    unsigned short* cp = cand + ((size_t)b*NN + n) * CANDS + w * MS;
    #pragma unroll
    for (int i = 0; i < MS; ++i) cp[i] = (unsigned short)idx[i];
}

// ---------------- Kernel 3: fp64 refine + gather + epilogue ----------------
__global__ __launch_bounds__(256, 2) void k_refine(
    const float* __restrict__ xt, const double* __restrict__ xxd,
    const unsigned short* __restrict__ cand,
    const float* __restrict__ yT, const float* __restrict__ zT,
    const float* __restrict__ gamma, const float* __restrict__ beta,
    const float* __restrict__ rmean, const float* __restrict__ rvar,
    float* __restrict__ out)
{
    __shared__ double scoreS[64][CANDS + 1];   // 49,664 B
    __shared__ int    selS[64][KK];            //  5,120 B
    int tid = threadIdx.x;
    int b  = blockIdx.x >> 6;
    int n0 = (blockIdx.x & 63) << 6;
    int r  = tid >> 2, g = tid & 3;
    int n  = n0 + r;

    // exact fp64 scores for this thread's 24 candidates
    {
        float xn[64];
        const float4* xnp = (const float4*)(xt + ((size_t)b*NN + n) * 64);
        #pragma unroll
        for (int i = 0; i < 16; ++i) {
            float4 v = xnp[i];
            xn[4*i] = v.x; xn[4*i+1] = v.y; xn[4*i+2] = v.z; xn[4*i+3] = v.w;
        }
        const unsigned short* cp = cand + ((size_t)b*NN + n) * CANDS + g * MS;
        for (int i = 0; i < MS; ++i) {
            int m = cp[i];
            const float4* xmp = (const float4*)(xt + ((size_t)b*NN + m) * 64);
            double acc = 0.0;
            #pragma unroll
            for (int c4 = 0; c4 < 16; ++c4) {
                float4 v = xmp[c4];
                acc += (double)xn[4*c4]   * (double)v.x;
                acc += (double)xn[4*c4+1] * (double)v.y;
                acc += (double)xn[4*c4+2] * (double)v.z;
                acc += (double)xn[4*c4+3] * (double)v.w;
            }
            scoreS[r][g*MS + i] = 2.0 * acc - xxd[b*NN + m];
        }
    }
    __syncthreads();

    // top-20 set selection (exact), one lane per row
    if (tid < 64) {
        int rr = tid;
        const unsigned short* cp = cand + ((size_t)b*NN + n0 + rr) * CANDS;
        #pragma unroll 1
        for (int k = 0; k < KK; ++k) {
            double best = -1e300; int bp = 0;
            #pragma unroll 1
            for (int p = 0; p < CANDS; ++p) {
                double sv = scoreS[rr][p];
                if (sv > best) { best = sv; bp = p; }
            }
            selS[rr][k] = cp[bp];
            scoreS[rr][bp] = -1e300;
        }
    }
    __syncthreads();

    // gather y for the 20 neighbors, min/max per o, epilogue
    float mn[16], mx[16];
    #pragma unroll
    for (int i = 0; i < 16; ++i) { mn[i] = __builtin_inff(); mx[i] = -__builtin_inff(); }
    #pragma unroll 1
    for (int k = 0; k < KK; ++k) {
        int m = selS[r][k];
        const float4* yp = (const float4*)(yT + ((size_t)b*NN + m) * 64 + g*16);
        #pragma unroll
        for (int q = 0; q < 4; ++q) {
            float4 v = yp[q];
            mn[4*q]   = fminf(mn[4*q],   v.x); mx[4*q]   = fmaxf(mx[4*q],   v.x);
            mn[4*q+1] = fminf(mn[4*q+1], v.y); mx[4*q+1] = fmaxf(mx[4*q+1], v.y);
            mn[4*q+2] = fminf(mn[4*q+2], v.z); mx[4*q+2] = fmaxf(mx[4*q+2], v.z);
            mn[4*q+3] = fminf(mn[4*q+3], v.w); mx[4*q+3] = fmaxf(mx[4*q+3], v.w);
        }
    }
    const float* zp = zT + ((size_t)b*NN + n) * 64 + g*16;
    #pragma unroll
    for (int i = 0; i < 16; ++i) {
        int o = g*16 + i;
        float inv  = gamma[o] / sqrtf(rvar[o] + 1e-5f);
        float bias = beta[o] - rmean[o] * inv;
        float ysel = (inv >= 0.f) ? mn[i] : mx[i];
        float h = (zp[i] - ysel) * inv + bias;
        out[((size_t)(b*OO + o) << 12) + n0 + r] = (h >= 0.f) ? h : 0.2f * h;
    }
}

extern "C" void kernel_launch(void* const* d_in, const int* in_sizes, int n_in,
                              void* d_out, int out_size, void* d_ws, size_t ws_size,
                              hipStream_t stream) {
    const float* x     = (const float*)d_in[0];
    const float* W     = (const float*)d_in[1];
    const float* gamma = (const float*)d_in[2];
    const float* beta  = (const float*)d_in[3];
    const float* rmean = (const float*)d_in[4];
    const float* rvar  = (const float*)d_in[5];
    float* out = (float*)d_out;

    char* ws = (char*)d_ws;
    float*  xt   = (float*) (ws);                                  // 8 MB
    float*  yT   = (float*) (ws + ((size_t)8  << 20));             // 8 MB
    float*  zT   = (float*) (ws + ((size_t)16 << 20));             // 8 MB
    double* xxd  = (double*)(ws + ((size_t)24 << 20));             // 256 KB
    float*  xxf  = (float*) (ws + ((size_t)24 << 20) + (512 << 10)); // 128 KB
    unsigned short* cand = (unsigned short*)(ws + ((size_t)25 << 20)); // 6 MB

    k_prep  <<<128, 256, 0, stream>>>(x, W, xt, yT, zT, xxd, xxf);
    k_topk  <<<512, 256, 0, stream>>>(xt, xxf, cand);
    k_refine<<<512, 256, 0, stream>>>(xt, xxd, cand, yT, zT,
                                      gamma, beta, rmean, rvar, out);
}

// Round 2
// 379.669 us; speedup vs baseline: 3.2189x; 3.2189x over previous
//
#include <hip/hip_runtime.h>
#include <hip/hip_bf16.h>

// EdgeConv B=8,C=64,N=4096,OUT=64,K=20.
// h[b,o,n,k] = z[b,n,o] - y[b,idx_k,o];  out = leakyrelu((z - min/max_k y)*inv + bias)
#define NN 4096
#define KK 20
#define LL 12        // per-thread sorted list (16 lists/row, multinomial-safe)
#define NCAND 192    // 16*LL
#define EXTR 36      // approx-top extracted before fp64 rescore (margin 16 over 20)

typedef short bf16x8 __attribute__((ext_vector_type(8)));
typedef float f32x4  __attribute__((ext_vector_type(4)));

__device__ __forceinline__ unsigned umax_(unsigned a, unsigned b){ return a > b ? a : b; }
__device__ __forceinline__ unsigned umin_(unsigned a, unsigned b){ return a < b ? a : b; }

__device__ __forceinline__ unsigned bfbits(float f) {   // fp32 -> bf16 bits, RNE
    unsigned u = __float_as_uint(f);
    return (u + 0x7FFFu + ((u >> 16) & 1u)) >> 16;
}

// ---------------- Kernel 1: transpose + xx + bf16 copy + y/z matvecs ----------------
__global__ __launch_bounds__(256, 2) void k_prep(
    const float* __restrict__ x, const float* __restrict__ W,
    float* __restrict__ xt, unsigned short* __restrict__ xbf,
    float* __restrict__ yT, float* __restrict__ zT,
    double* __restrict__ xxd, float* __restrict__ xxf)
{
    __shared__ float wS[8192];           // W row-major [o][128], 32 KB
    int tid = threadIdx.x;
    #pragma unroll
    for (int i = 0; i < 32; ++i) wS[tid + 256*i] = W[tid + 256*i];
    __syncthreads();

    int b = blockIdx.x >> 4;
    int n = ((blockIdx.x & 15) << 8) + tid;

    float xv[64];
    double xx = 0.0;
    #pragma unroll
    for (int c = 0; c < 64; ++c) {
        float v = x[((size_t)(b*64 + c) << 12) + n];
        xv[c] = v;
        xx += (double)v * (double)v;
    }
    size_t rowbase = ((size_t)b*NN + n) * 64;
    #pragma unroll
    for (int c4 = 0; c4 < 16; ++c4)
        ((float4*)(xt + rowbase))[c4] =
            make_float4(xv[4*c4], xv[4*c4+1], xv[4*c4+2], xv[4*c4+3]);
    // bf16 row (RNE), packed 2/dword
    {
        unsigned pk[32];
        #pragma unroll
        for (int i = 0; i < 32; ++i)
            pk[i] = bfbits(xv[2*i]) | (bfbits(xv[2*i+1]) << 16);
        uint4* dst = (uint4*)(xbf + rowbase);
        #pragma unroll
        for (int i = 0; i < 8; ++i)
            dst[i] = make_uint4(pk[4*i], pk[4*i+1], pk[4*i+2], pk[4*i+3]);
    }
    xxd[b*NN + n] = xx;
    xxf[b*NN + n] = (float)xx;

    for (int o0 = 0; o0 < 64; o0 += 16) {
        float yv[16], zv[16];
        #pragma unroll
        for (int i = 0; i < 16; ++i) {
            const float* w1 = wS + (size_t)(o0 + i) * 128;
            float a1 = 0.f, a2 = 0.f;
            #pragma unroll
            for (int c = 0; c < 64; ++c) {
                a1 = fmaf(w1[c],      xv[c], a1);
                a2 = fmaf(w1[64 + c], xv[c], a2);
            }
            yv[i] = a1; zv[i] = a1 + a2;
        }
        float4* yp = (float4*)(yT + rowbase + o0);
        float4* zp = (float4*)(zT + rowbase + o0);
        #pragma unroll
        for (int i4 = 0; i4 < 4; ++i4) {
            yp[i4] = make_float4(yv[4*i4], yv[4*i4+1], yv[4*i4+2], yv[4*i4+3]);
            zp[i4] = make_float4(zv[4*i4], zv[4*i4+1], zv[4*i4+2], zv[4*i4+3]);
        }
    }
}

// ---------------- Kernel 2: MFMA Gram + branchless per-thread top-12 ----------------
// block = 4 waves, 16 n-rows. Wave w owns m-cols [16w..16w+16) of each 64-m chunk.
// Barrier-free: each wave writes & re-reads only its own LDS columns (DS in-order/wave).
__global__ __launch_bounds__(256) void k_topk(
    const unsigned short* __restrict__ xbf, const float* __restrict__ xxf,
    unsigned* __restrict__ cand)
{
    __shared__ float scoreS[16 * 68];    // pitch 68 (16B-aligned rows, conflict-benign)
    int tid  = threadIdx.x;
    int w    = tid >> 6, lane = tid & 63;
    int quad = lane >> 4, c = lane & 15;
    int b  = blockIdx.x >> 8;
    int n0 = (blockIdx.x & 255) << 4;

    const uint4* xb = (const uint4*)xbf;      // one x-row = 8 uint4

    // A fragments: row n0+c, k = quad*8+j (+32)
    size_t arow = ((size_t)b*NN + n0 + c) * 8 + quad;
    bf16x8 a0 = __builtin_bit_cast(bf16x8, xb[arow]);
    bf16x8 a1 = __builtin_bit_cast(bf16x8, xb[arow + 4]);

    unsigned keys[LL];
    #pragma unroll
    for (int i = 0; i < LL; ++i) keys[i] = 0u;

    size_t bbase = ((size_t)b*NN + 16*w + c) * 8 + quad;
    uint4 pb0 = xb[bbase], pb1 = xb[bbase + 4];
    float pxx = xxf[b*NN + 16*w + c];

    #pragma unroll 1
    for (int chunk = 0; chunk < 64; ++chunk) {
        uint4 cb0 = pb0, cb1 = pb1;
        float xxm = pxx;
        if (chunk < 63) {
            size_t nb = bbase + (size_t)(chunk + 1) * 64 * 8;
            pb0 = xb[nb]; pb1 = xb[nb + 4];
            pxx = xxf[b*NN + (chunk + 1)*64 + 16*w + c];
        }
        f32x4 acc = __builtin_amdgcn_mfma_f32_16x16x32_bf16(
            a0, __builtin_bit_cast(bf16x8, cb0), (f32x4){0.f,0.f,0.f,0.f}, 0, 0, 0);
        acc = __builtin_amdgcn_mfma_f32_16x16x32_bf16(
            a1, __builtin_bit_cast(bf16x8, cb1), acc, 0, 0, 0);

        // D layout: col=lane&15 (m), row=quad*4+reg (n). score = 2*dot - xx[m]
        int wb = (w << 4) + c;
        #pragma unroll
        for (int j = 0; j < 4; ++j)
            scoreS[(quad*4 + j)*68 + wb] = fmaf(2.f, acc[j], -xxm);

        // scan (same wave's columns): row = lane&15, cols 16w + 4*quad..+4
        const float4* sv = (const float4*)(scoreS + c*68 + (w << 4) + (quad << 2));
        float4 s4 = *sv;
        int mbase = (chunk << 6) + (w << 4) + (quad << 2);
        float ss[4] = {s4.x, s4.y, s4.z, s4.w};
        #pragma unroll
        for (int j = 0; j < 4; ++j) {
            unsigned u = __float_as_uint(ss[j]);
            u ^= (unsigned)(((int)u) >> 31) | 0x80000000u;
            unsigned key = (u & 0xFFFF0000u) | (unsigned)(mbase + j);
            #pragma unroll
            for (int t = 0; t < LL; ++t) {      // sorted compare-exchange insert
                unsigned mx = umax_(keys[t], key);
                key = umin_(keys[t], key);
                keys[t] = mx;
            }
        }
    }

    // row = c (lane&15), list id = w*4+quad
    unsigned* cp = cand + ((size_t)(b*NN + n0 + c)) * NCAND + (w*4 + quad) * LL;
    #pragma unroll
    for (int i = 0; i < LL; ++i) cp[i] = keys[i];
}

// ---------------- Kernel 3: merge + fp64 refine + gather + epilogue ----------------
__global__ __launch_bounds__(256) void k_refine(
    const float* __restrict__ xt, const double* __restrict__ xxd,
    const unsigned* __restrict__ cand,
    const float* __restrict__ yT, const float* __restrict__ zT,
    const float* __restrict__ gamma, const float* __restrict__ beta,
    const float* __restrict__ rmean, const float* __restrict__ rvar,
    float* __restrict__ out)
{
    __shared__ float    xnS[16 * 64];          //  4 KB
    __shared__ unsigned keysL[16 * NCAND];     // 12 KB
    __shared__ unsigned selK[16 * EXTR];       //  2.3 KB
    __shared__ double   selD[16 * EXTR];       //  4.6 KB
    __shared__ int      selS[16 * KK];         //  1.3 KB
    __shared__ float    outS[64 * 20];         //  5 KB

    int tid = threadIdx.x;
    int r = tid >> 4, g = tid & 15;            // 16 threads per row, quarter-wave = row
    int b = blockIdx.x >> 8;
    int n0 = (blockIdx.x & 255) << 4;
    int n = n0 + r;

    ((float4*)xnS)[tid] = ((const float4*)(xt + ((size_t)b*NN + n0) * 64))[tid];
    {
        const uint4* cs = (const uint4*)(cand + ((size_t)(b*NN + n0)) * NCAND);
        uint4* kd = (uint4*)keysL;
        kd[tid] = cs[tid]; kd[tid + 256] = cs[tid + 256]; kd[tid + 512] = cs[tid + 512];
    }
    __syncthreads();

    // extract approx-top-EXTR by 16-way merge of sorted 12-lists (quarter-wave max)
    {
        int head = 0;
        #pragma unroll 1
        for (int it = 0; it < EXTR; ++it) {
            unsigned v = (head < LL) ? keysL[r*NCAND + g*LL + head] : 0u;
            unsigned vm = v;
            #pragma unroll
            for (int o = 1; o < 16; o <<= 1) vm = umax_(vm, __shfl_xor(vm, o, 16));
            if (v == vm && head < LL) { selK[r*EXTR + it] = v; ++head; }
        }
    }
    __syncthreads();

    // fp64 exact rescore of the EXTR candidates
    for (int i = g; i < EXTR; i += 16) {
        unsigned key = selK[r*EXTR + i];
        int m = (int)(key & 0xFFFFu);
        const float4* xm  = (const float4*)(xt + ((size_t)b*NN + m) * 64);
        const float4* xn4 = (const float4*)(xnS + r*64);
        double acc = 0.0;
        #pragma unroll
        for (int kk2 = 0; kk2 < 16; ++kk2) {
            float4 a = xn4[kk2], v = xm[kk2];
            acc += (double)a.x*(double)v.x + (double)a.y*(double)v.y
                 + (double)a.z*(double)v.z + (double)a.w*(double)v.w;
        }
        selD[r*EXTR + i] = 2.0*acc - xxd[b*NN + m];
    }
    __syncthreads();

    // exact top-20 set by rank counting (fp64 scores distinct a.s.)
    for (int i = g; i < EXTR; i += 16) {
        double si = selD[r*EXTR + i];
        int cnt = 0;
        #pragma unroll 1
        for (int p = 0; p < EXTR; ++p) cnt += (selD[r*EXTR + p] > si) ? 1 : 0;
        if (cnt < KK) selS[r*KK + cnt] = (int)(selK[r*EXTR + i] & 0xFFFFu);
    }
    __syncthreads();

    // gather y over the 20 neighbors; min & max per o; epilogue
    float mn[4] = { __builtin_inff(), __builtin_inff(), __builtin_inff(), __builtin_inff() };
    float mx[4] = { -__builtin_inff(), -__builtin_inff(), -__builtin_inff(), -__builtin_inff() };
    #pragma unroll 1
    for (int k = 0; k < KK; ++k) {
        int m = selS[r*KK + k];
        float4 y4 = *(const float4*)(yT + ((size_t)b*NN + m) * 64 + 4*g);
        mn[0] = fminf(mn[0], y4.x); mx[0] = fmaxf(mx[0], y4.x);
        mn[1] = fminf(mn[1], y4.y); mx[1] = fmaxf(mx[1], y4.y);
        mn[2] = fminf(mn[2], y4.z); mx[2] = fmaxf(mx[2], y4.z);
        mn[3] = fminf(mn[3], y4.w); mx[3] = fmaxf(mx[3], y4.w);
    }
    float4 z4 = *(const float4*)(zT + ((size_t)b*NN + n) * 64 + 4*g);
    float zz[4] = {z4.x, z4.y, z4.z, z4.w};
    #pragma unroll
    for (int j = 0; j < 4; ++j) {
        int o = 4*g + j;
        float inv  = gamma[o] / sqrtf(rvar[o] + 1e-5f);
        float bias = beta[o] - rmean[o] * inv;
        float ysel = (inv >= 0.f) ? mn[j] : mx[j];
        float h = (zz[j] - ysel) * inv + bias;
        outS[o*20 + r] = (h >= 0.f) ? h : 0.2f * h;
    }
    __syncthreads();
    // coalesced-ish transpose store: thread -> (o = tid>>2, q = tid&3)
    {
        int o = tid >> 2, q = tid & 3;
        float4 v = *(const float4*)(outS + o*20 + 4*q);
        *(float4*)(out + ((size_t)(b*64 + o)) * NN + n0 + 4*q) = v;
    }
}

extern "C" void kernel_launch(void* const* d_in, const int* in_sizes, int n_in,
                              void* d_out, int out_size, void* d_ws, size_t ws_size,
                              hipStream_t stream) {
    const float* x     = (const float*)d_in[0];
    const float* W     = (const float*)d_in[1];
    const float* gamma = (const float*)d_in[2];
    const float* beta  = (const float*)d_in[3];
    const float* rmean = (const float*)d_in[4];
    const float* rvar  = (const float*)d_in[5];
    float* out = (float*)d_out;

    char* ws = (char*)d_ws;
    float*          xt   = (float*)          (ws);                          //  8 MB
    unsigned short* xbf  = (unsigned short*) (ws + ((size_t) 8 << 20));     //  4 MB
    float*          yT   = (float*)          (ws + ((size_t)12 << 20));     //  8 MB
    float*          zT   = (float*)          (ws + ((size_t)20 << 20));     //  8 MB
    double*         xxd  = (double*)         (ws + ((size_t)28 << 20));     // 256 KB
    float*          xxf  = (float*)          (ws + ((size_t)28 << 20) + (512 << 10)); // 128 KB
    unsigned*       cand = (unsigned*)       (ws + ((size_t)29 << 20));     // 24 MB

    k_prep  <<< 128, 256, 0, stream>>>(x, W, xt, xbf, yT, zT, xxd, xxf);
    k_topk  <<<2048, 256, 0, stream>>>(xbf, xxf, cand);
    k_refine<<<2048, 256, 0, stream>>>(xt, xxd, cand, yT, zT,
                                       gamma, beta, rmean, rvar, out);
}